// Round 17
// baseline (21.481 us; speedup 1.0000x reference)
//
#include <hip/hip_runtime.h>

constexpr int NQ = 7;
constexpr int NL = 4;
constexpr int NG = NL * NQ;   // 28
constexpr int NCLS = 22;
constexpr int EPB = 32;       // elements per 256-thread block: 16 groups x 2 streams

typedef float v2 __attribute__((ext_vector_type(2)));
#define FMA2(a,b,c) __builtin_elementwise_fma((a),(b),(c))

__device__ __forceinline__ v2 sp(float s) { v2 r; r.x = s; r.y = s; return r; }
__device__ __forceinline__ v2 mkv2(float a, float b) { v2 r; r.x = a; r.y = b; return r; }
__device__ __forceinline__ v2 sel(bool c, v2 a, v2 b) {
    v2 r; r.x = c ? a.x : b.x; r.y = c ? a.y : b.y; return r;
}

// ---------------- cross-lane primitives (all HW-proven R1..R16) ----------------
template<int CTRL>
__device__ __forceinline__ float fdpp(float v) {
    return __int_as_float(__builtin_amdgcn_mov_dpp(__float_as_int(v), CTRL, 0xF, 0xF, true));
}
template<int OFF>
__device__ __forceinline__ float fswz(float v) {
    return __int_as_float(__builtin_amdgcn_ds_swizzle(__float_as_int(v), OFF));
}
template<int M>
__device__ __forceinline__ float xorl(float v) {
    if      constexpr (M == 1)  return fdpp<0xB1>(v);    // quad_perm [1,0,3,2]
    else if constexpr (M == 2)  return fdpp<0x4E>(v);    // quad_perm [2,3,0,1]
    else if constexpr (M == 4)  return fswz<0x101F>(v);  // xor4
    else                        return fdpp<0x128>(v);   // ROW_ROR:8 == xor8 (R12-proven)
}
template<int M>
__device__ __forceinline__ v2 shufv(v2 v) {
    v2 r; r.x = xorl<M>(v.x); r.y = xorl<M>(v.y); return r;
}

// ---------------- fused gate build: U' = U_rot @ RX(c,s) ----------------
__device__ __forceinline__ void fuse(const float* __restrict__ u, float c, float s,
                                     float4& A, float4& B) {
    A.x = fmaf(c, u[0],  s * u[3]);  A.y = fmaf(c, u[1], -s * u[2]);
    A.z = fmaf(c, u[2],  s * u[1]);  A.w = fmaf(c, u[3], -s * u[0]);
    B.x = fmaf(c, u[4],  s * u[7]);  B.y = fmaf(c, u[5], -s * u[6]);
    B.z = fmaf(c, u[6],  s * u[5]);  B.w = fmaf(c, u[7], -s * u[4]);
}

// lane-bit gate (mask M): packed state, scalar coefficient broadcast
template<int M>
__device__ __forceinline__ void gateLane(int lane, float4 A, float4 B,
                                         v2 X[4], v2 Y[4]) {
    const bool hi = (lane & M) != 0;
    const float cvr = hi ? B.z : A.x, cvi = hi ? B.w : A.y;   // diag
    const float cwr = hi ? B.x : A.z, cwi = hi ? B.y : A.w;   // off-diag
    v2 Xs[4], Ys[4];
    #pragma unroll
    for (int j = 0; j < 4; ++j) { Xs[j] = shufv<M>(X[j]); Ys[j] = shufv<M>(Y[j]); }
    #pragma unroll
    for (int j = 0; j < 4; ++j) {
        v2 nX = FMA2(sp(cvr), X[j], FMA2(sp(-cvi), Y[j], FMA2(sp(cwr), Xs[j], sp(-cwi)*Ys[j])));
        v2 nY = FMA2(sp(cvr), Y[j], FMA2(sp( cvi), X[j], FMA2(sp(cwr), Ys[j], sp( cwi)*Xs[j])));
        X[j] = nX; Y[j] = nY;
    }
}

// cross-register gate: reg ja = row-A role, reg jb = row-B role
__device__ __forceinline__ void gateCross(float4 A, float4 B,
                                          v2& Xa, v2& Ya, v2& Xb, v2& Yb) {
    v2 nXa = FMA2(sp(A.x), Xa, FMA2(sp(-A.y), Ya, FMA2(sp(A.z), Xb, sp(-A.w)*Yb)));
    v2 nYa = FMA2(sp(A.x), Ya, FMA2(sp( A.y), Xa, FMA2(sp(A.z), Yb, sp( A.w)*Xb)));
    v2 nXb = FMA2(sp(B.x), Xa, FMA2(sp(-B.y), Ya, FMA2(sp(B.z), Xb, sp(-B.w)*Yb)));
    v2 nYb = FMA2(sp(B.x), Ya, FMA2(sp( B.y), Xa, FMA2(sp(B.z), Yb, sp( B.w)*Xb)));
    Xa = nXa; Ya = nYa; Xb = nXb; Yb = nYb;
}

// q5 (component) gate: paired coefficients, applied to one stream
__device__ __forceinline__ void gateComp(const v2* __restrict__ tp, v2 X[4], v2 Y[4]) {
    const v2 c00r = tp[0], c00i = tp[1], c01r = tp[2], c01i = tp[3];
    #pragma unroll
    for (int j = 0; j < 4; ++j) {
        const v2 Xxx = X[j].xx, Xyy = X[j].yy;
        const v2 Yxx = Y[j].xx, Yyy = Y[j].yy;
        v2 nX = FMA2(c00r, Xxx, FMA2(-c00i, Yxx, FMA2(c01r, Xyy, (-c01i)*Yyy)));
        v2 nY = FMA2(c00r, Yxx, FMA2( c00i, Xxx, FMA2(c01r, Yyy, ( c01i)*Xyy)));
        X[j] = nX; Y[j] = nY;
    }
}

// CNOT tail after the merged gather (one stream)
__device__ __forceinline__ void cnotTail(int lane, int srcLane, v2 X[4], v2 Y[4]) {
    #pragma unroll
    for (int j = 0; j < 4; ++j) {
        X[j].x = __shfl(X[j].x, srcLane); X[j].y = __shfl(X[j].y, srcLane);
        Y[j].x = __shfl(Y[j].x, srcLane); Y[j].y = __shfl(Y[j].y, srcLane);
    }
    {   // (3,4): ctrl u0, tgt k2 -> cond swap regs (0<->2),(1<->3)
        const bool cc = (lane & 1) != 0;
        v2 t;
        t = X[0]; X[0] = sel(cc, X[2], X[0]); X[2] = sel(cc, t, X[2]);
        t = X[1]; X[1] = sel(cc, X[3], X[1]); X[3] = sel(cc, t, X[3]);
        t = Y[0]; Y[0] = sel(cc, Y[2], Y[0]); Y[2] = sel(cc, t, Y[2]);
        t = Y[1]; Y[1] = sel(cc, Y[3], Y[1]); Y[3] = sel(cc, t, Y[3]);
    }
    // (4,5): ctrl k2 (regs 2,3), tgt k1 -> component swap
    X[2] = X[2].yx; X[3] = X[3].yx; Y[2] = Y[2].yx; Y[3] = Y[3].yx;
    {   // (5,6): ctrl k1 (.y comps), tgt k0 -> swap .y across reg-bit0 pairs
        float t;
        t = X[0].y; X[0].y = X[1].y; X[1].y = t;
        t = X[2].y; X[2].y = X[3].y; X[3].y = t;
        t = Y[0].y; Y[0].y = Y[1].y; Y[1].y = t;
        t = Y[2].y; Y[2].y = Y[3].y; Y[3].y = t;
    }
    // (6,0): ctrl k0 (regs 1,3), tgt u3 -> xor8 whole regs (DPP)
    X[1] = shufv<8>(X[1]); X[3] = shufv<8>(X[3]);
    Y[1] = shufv<8>(Y[1]); Y[3] = shufv<8>(Y[3]);
}

// ---------------- main kernel: 2 independent elements PER THREAD ----------------
// 16-lane group grp (0..15) owns elements b0 = blk*32+grp, b1 = b0+16 — two
// fully independent dependency chains interleaved by the scheduler (ILP probe).
// Layout per stream identical to R14/R16: amp a6..a0 = u3 u2 u1 u0 k2 k1 k0;
// reg j=(k2<<1)|k0, component k1; q0->u3(m8) q1->u2(m4) q2->u1(m2) q3->u0(m1).
__global__ __launch_bounds__(256) void reupload_kernel(
    const float* __restrict__ x,       // (B,7)
    const float* __restrict__ wts,     // (4,7,3)
    const float* __restrict__ fc1_w,   // (32,7)
    const float* __restrict__ fc1_b,   // (32,)
    const float* __restrict__ fc2_w,   // (22,32)
    const float* __restrict__ fc2_b,   // (22,)
    float* __restrict__ out,           // (B,22)
    int B)
{
    __shared__ __align__(16) float rotU[NG * 8];        // 28 Rot matrices
    __shared__ float2 csb[EPB * NQ];                    // per-element RX (c,s)
    __shared__ __align__(16) float fU[NG * EPB * 8];    // fused matrices (28.7 KB)
    __shared__ __align__(16) float fUT[NL * EPB * 8];   // q5 transposed coefs (4 KB)
    __shared__ __align__(16) float hbuf[EPB][32];       // MLP hidden (4 KB)

    const int tid = threadIdx.x;
    // --- phase 0: c,s (224 thr) ∥ Rot matrices (28 thr, tid 224..251) ---
    if (tid < EPB * NQ) {
        const int e = tid / NQ, q = tid % NQ;
        const int bb = blockIdx.x * EPB + e;
        const float xv = (bb < B) ? x[bb*NQ + q] : 0.f;
        const float h = 0.5f * xv;
        csb[tid] = make_float2(__cosf(h), __sinf(h));
    } else if (tid >= 224 && tid < 224 + NG) {
        const int g = tid - 224;
        float phi = wts[g*3+0], th = wts[g*3+1], om = wts[g*3+2];
        float ct = __cosf(0.5f*th), st = __sinf(0.5f*th);
        float ap = 0.5f*(phi+om),  am = 0.5f*(phi-om);
        float cp = __cosf(ap), sp_ = __sinf(ap);
        float cm = __cosf(am), sm = __sinf(am);
        float* u = &rotU[g*8];
        u[0] =  cp*ct; u[1] = -sp_*ct;  // u00 = ep*ct        (ep = cp - i sp)
        u[2] = -cm*st; u[3] = -sm*st;   // u01 = -conj(em)*st (em = cm - i sm)
        u[4] =  cm*st; u[5] = -sm*st;   // u10 = em*st
        u[6] =  cp*ct; u[7] =  sp_*ct;  // u11 = conj(ep)*ct
    }
    __syncthreads();
    // --- phase 1: build fused matrices (896 jobs, stride loop) ---
    #pragma unroll
    for (int i = tid; i < NG * EPB; i += 256) {
        const int g = i >> 5, e = i & 31;
        const int q = g % NQ;
        const float2 cs = csb[e*NQ + q];
        float4 A, Bq;
        fuse(&rotU[g*8], cs.x, cs.y, A, Bq);
        float4* dst = reinterpret_cast<float4*>(&fU[(g*EPB + e)*8]);
        dst[0] = A; dst[1] = Bq;
        if (q == 5) {   // {(u00r,u10r),(u00i,u10i),(u01r,u11r),(u01i,u11i)}
            const int l = g / NQ;
            float* td = &fUT[(l*EPB + e)*8];
            td[0] = A.x; td[1] = Bq.x; td[2] = A.y; td[3] = Bq.y;
            td[4] = A.z; td[5] = Bq.z; td[6] = A.w; td[7] = Bq.w;
        }
    }
    __syncthreads();

    const int lane = threadIdx.x & 63;
    const int u    = threadIdx.x & 15;          // in-group lane
    const int grp  = threadIdx.x >> 4;          // group slot (0..15)
    const int b0   = blockIdx.x * EPB + grp;    // stream 0 element
    const int b1   = b0 + 16;                   // stream 1 element
    if (b0 >= B) return;

    // merged CNOT(0,1)(1,2)(2,3) gather source (R11-proven)
    const int srcLane = (lane & 48) | ((u ^ (u >> 1)) & 15);

    v2 X0[4], Y0[4], X1[4], Y1[4];
    #pragma unroll
    for (int j = 0; j < 4; ++j) {
        X0[j] = sp(0.f); Y0[j] = sp(0.f);
        X1[j] = sp(0.f); Y1[j] = sp(0.f);
    }
    X0[0].x = (u == 0) ? 1.f : 0.f;
    X1[0].x = (u == 0) ? 1.f : 0.f;

    #pragma unroll
    for (int l = 0; l < NL; ++l) {
        float4 A0, B0, A1, B1;
        #define LOADU2(q) { \
            const float4* p0 = reinterpret_cast<const float4*>(&fU[((l*NQ + (q))*EPB + grp)*8]); \
            A0 = p0[0]; B0 = p0[1]; \
            const float4* p1 = reinterpret_cast<const float4*>(&fU[((l*NQ + (q))*EPB + grp + 16)*8]); \
            A1 = p1[0]; B1 = p1[1]; }
        LOADU2(0); gateLane<8>(lane, A0, B0, X0, Y0); gateLane<8>(lane, A1, B1, X1, Y1);
        LOADU2(1); gateLane<4>(lane, A0, B0, X0, Y0); gateLane<4>(lane, A1, B1, X1, Y1);
        LOADU2(2); gateLane<2>(lane, A0, B0, X0, Y0); gateLane<2>(lane, A1, B1, X1, Y1);
        LOADU2(3); gateLane<1>(lane, A0, B0, X0, Y0); gateLane<1>(lane, A1, B1, X1, Y1);
        LOADU2(4);                                   // q4 -> k2: reg pairs (0,2),(1,3)
        gateCross(A0, B0, X0[0], Y0[0], X0[2], Y0[2]);
        gateCross(A0, B0, X0[1], Y0[1], X0[3], Y0[3]);
        gateCross(A1, B1, X1[0], Y1[0], X1[2], Y1[2]);
        gateCross(A1, B1, X1[1], Y1[1], X1[3], Y1[3]);
        gateComp(reinterpret_cast<const v2*>(&fUT[(l*EPB + grp)*8]),      X0, Y0);
        gateComp(reinterpret_cast<const v2*>(&fUT[(l*EPB + grp + 16)*8]), X1, Y1);
        LOADU2(6);                                   // q6 -> k0: reg pairs (0,1),(2,3)
        gateCross(A0, B0, X0[0], Y0[0], X0[1], Y0[1]);
        gateCross(A0, B0, X0[2], Y0[2], X0[3], Y0[3]);
        gateCross(A1, B1, X1[0], Y1[0], X1[1], Y1[1]);
        gateCross(A1, B1, X1[2], Y1[2], X1[3], Y1[3]);
        #undef LOADU2

        cnotTail(lane, srcLane, X0, Y0);
        cnotTail(lane, srcLane, X1, Y1);
    }

    // ---------- <Z_j> + MLP for both streams ----------
    v2 zv0[3], zv1[3]; float z6_0, z6_1;
    {
        v2 P[4];
        #pragma unroll
        for (int j = 0; j < 4; ++j) P[j] = FMA2(X0[j], X0[j], Y0[j]*Y0[j]);
        const v2 Sa = P[0] + P[1], Sb = P[2] + P[3];
        const v2 Se = P[0] + P[2], So = P[1] + P[3];
        const v2 T  = Sa + Sb;
        const float t = T.x + T.y;
        zv0[0] = mkv2((lane & 8) ? -t : t, (lane & 4) ? -t : t);
        zv0[1] = mkv2((lane & 2) ? -t : t, (lane & 1) ? -t : t);
        zv0[2] = mkv2((Sa.x + Sa.y) - (Sb.x + Sb.y), T.x - T.y);
        z6_0 = (Se.x + Se.y) - (So.x + So.y);
    }
    {
        v2 P[4];
        #pragma unroll
        for (int j = 0; j < 4; ++j) P[j] = FMA2(X1[j], X1[j], Y1[j]*Y1[j]);
        const v2 Sa = P[0] + P[1], Sb = P[2] + P[3];
        const v2 Se = P[0] + P[2], So = P[1] + P[3];
        const v2 T  = Sa + Sb;
        const float t = T.x + T.y;
        zv1[0] = mkv2((lane & 8) ? -t : t, (lane & 4) ? -t : t);
        zv1[1] = mkv2((lane & 2) ? -t : t, (lane & 1) ? -t : t);
        zv1[2] = mkv2((Sa.x + Sa.y) - (Sb.x + Sb.y), T.x - T.y);
        z6_1 = (Se.x + Se.y) - (So.x + So.y);
    }
    // 16-lane reductions (R12-proven chain), both streams interleavable
    #pragma unroll
    for (int j = 0; j < 3; ++j) {
        v2 v = zv0[j];
        v2 s1; s1.x = xorl<1>(v.x); s1.y = xorl<1>(v.y); v += s1;
        v2 s2; s2.x = xorl<2>(v.x); s2.y = xorl<2>(v.y); v += s2;
        v2 q4;  q4.x  = fdpp<0x124>(v.x); q4.y  = fdpp<0x124>(v.y);
        v2 q8;  q8.x  = fdpp<0x128>(v.x); q8.y  = fdpp<0x128>(v.y);
        v2 q12; q12.x = fdpp<0x12C>(v.x); q12.y = fdpp<0x12C>(v.y);
        zv0[j] = (v + q8) + (q4 + q12);
        v2 w = zv1[j];
        v2 t1; t1.x = xorl<1>(w.x); t1.y = xorl<1>(w.y); w += t1;
        v2 t2; t2.x = xorl<2>(w.x); t2.y = xorl<2>(w.y); w += t2;
        v2 r4;  r4.x  = fdpp<0x124>(w.x); r4.y  = fdpp<0x124>(w.y);
        v2 r8;  r8.x  = fdpp<0x128>(w.x); r8.y  = fdpp<0x128>(w.y);
        v2 r12; r12.x = fdpp<0x12C>(w.x); r12.y = fdpp<0x12C>(w.y);
        zv1[j] = (w + r8) + (r4 + r12);
    }
    {
        float v = z6_0;
        v += xorl<1>(v); v += xorl<2>(v);
        const float q4 = fdpp<0x124>(v), q8 = fdpp<0x128>(v), q12 = fdpp<0x12C>(v);
        z6_0 = (v + q8) + (q4 + q12);
        float w = z6_1;
        w += xorl<1>(w); w += xorl<2>(w);
        const float r4 = fdpp<0x124>(w), r8 = fdpp<0x128>(w), r12 = fdpp<0x12C>(w);
        z6_1 = (w + r8) + (r4 + r12);
    }

    // fc1 for both streams (2 rows/lane each)
    const float* wra = fc1_w + u*NQ;
    const float* wrb = fc1_w + (u+16)*NQ;
    {
        v2 da = FMA2(zv0[0], mkv2(wra[0], wra[1]),
                FMA2(zv0[1], mkv2(wra[2], wra[3]), zv0[2] * mkv2(wra[4], wra[5])));
        v2 db = FMA2(zv0[0], mkv2(wrb[0], wrb[1]),
                FMA2(zv0[1], mkv2(wrb[2], wrb[3]), zv0[2] * mkv2(wrb[4], wrb[5])));
        hbuf[grp][u]      = fmaxf(fc1_b[u]      + da.x + da.y + z6_0 * wra[6], 0.f);
        hbuf[grp][u + 16] = fmaxf(fc1_b[u + 16] + db.x + db.y + z6_0 * wrb[6], 0.f);
        v2 dc = FMA2(zv1[0], mkv2(wra[0], wra[1]),
                FMA2(zv1[1], mkv2(wra[2], wra[3]), zv1[2] * mkv2(wra[4], wra[5])));
        v2 dd = FMA2(zv1[0], mkv2(wrb[0], wrb[1]),
                FMA2(zv1[1], mkv2(wrb[2], wrb[3]), zv1[2] * mkv2(wrb[4], wrb[5])));
        hbuf[grp + 16][u]      = fmaxf(fc1_b[u]      + dc.x + dc.y + z6_1 * wra[6], 0.f);
        hbuf[grp + 16][u + 16] = fmaxf(fc1_b[u + 16] + dd.x + dd.y + z6_1 * wrb[6], 0.f);
    }
    __builtin_amdgcn_wave_barrier();
    asm volatile("s_waitcnt lgkmcnt(0)" ::: "memory");
    __builtin_amdgcn_sched_barrier(0);

    // fc2 for both streams
    const int kb = (u < NCLS - 16) ? (u + 16) : 0;
    const float4* w4a = reinterpret_cast<const float4*>(fc2_w + u*32);
    const float4* w4b = reinterpret_cast<const float4*>(fc2_w + kb*32);
    v2 a0 = sp(0.f), b0v = sp(0.f), a1 = sp(0.f), b1v = sp(0.f);
    #pragma unroll
    for (int i = 0; i < 8; ++i) {
        float4 h0 = *reinterpret_cast<const float4*>(&hbuf[grp][i*4]);
        float4 h1 = *reinterpret_cast<const float4*>(&hbuf[grp + 16][i*4]);
        float4 wa = w4a[i], wb = w4b[i];
        a0  = FMA2(mkv2(h0.x, h0.y), mkv2(wa.x, wa.y), a0);
        a0  = FMA2(mkv2(h0.z, h0.w), mkv2(wa.z, wa.w), a0);
        b0v = FMA2(mkv2(h0.x, h0.y), mkv2(wb.x, wb.y), b0v);
        b0v = FMA2(mkv2(h0.z, h0.w), mkv2(wb.z, wb.w), b0v);
        a1  = FMA2(mkv2(h1.x, h1.y), mkv2(wa.x, wa.y), a1);
        a1  = FMA2(mkv2(h1.z, h1.w), mkv2(wa.z, wa.w), a1);
        b1v = FMA2(mkv2(h1.x, h1.y), mkv2(wb.x, wb.y), b1v);
        b1v = FMA2(mkv2(h1.z, h1.w), mkv2(wb.z, wb.w), b1v);
    }
    out[b0*NCLS + u] = fc2_b[u] + a0.x + a0.y;
    if (u < NCLS - 16) out[b0*NCLS + 16 + u] = fc2_b[kb] + b0v.x + b0v.y;
    if (b1 < B) {
        out[b1*NCLS + u] = fc2_b[u] + a1.x + a1.y;
        if (u < NCLS - 16) out[b1*NCLS + 16 + u] = fc2_b[kb] + b1v.x + b1v.y;
    }
}

extern "C" void kernel_launch(void* const* d_in, const int* in_sizes, int n_in,
                              void* d_out, int out_size, void* d_ws, size_t ws_size,
                              hipStream_t stream) {
    const float* x     = (const float*)d_in[0];
    const float* wts   = (const float*)d_in[1];
    const float* fc1_w = (const float*)d_in[2];
    const float* fc1_b = (const float*)d_in[3];
    const float* fc2_w = (const float*)d_in[4];
    const float* fc2_b = (const float*)d_in[5];
    float* out = (float*)d_out;

    const int B = in_sizes[0] / NQ;            // 16384
    const int grid = (B + EPB - 1) / EPB;      // 512 blocks
    reupload_kernel<<<grid, 256, 0, stream>>>(x, wts, fc1_w, fc1_b, fc2_w, fc2_b, out, B);
}